// Round 5
// baseline (93.013 us; speedup 1.0000x reference)
//
#include <hip/hip_runtime.h>
#include <math.h>

// Problem constants (from reference)
#define FDIM 768
#define RNUM 7
#define BDIM 4096
#define DDIM 14
#define BD (BDIM * DDIM)          // 57344 rows
#define RF (RNUM * FDIM)          // 5376
#define NCHUNK 8                  // g-split for Kp fold (48 blocks in B)
#define GPC (FDIM / NCHUNK)       // 96
#define SCALE 0.03608439182435161f  // 768^-0.5

// Kernel C: 512 blocks x 8 waves = 4096 waves; 3 quad-iters (12 rows) +
// 1 pair-tail (2 rows) = 14 rows/wave = 57344 total.
#define CNW 4096
#define TAILBASE (CNW * 12)       // 49152

typedef float f4v __attribute__((ext_vector_type(4)));

// ---------------------------------------------------------------------------
// Wave-wide sum via DPP (VALU pipe) — verified correct across rounds.
// ---------------------------------------------------------------------------
#define DPP_ADD(x, ctrl)                                                      \
    x += __int_as_float(__builtin_amdgcn_update_dpp(                          \
        0, __float_as_int(x), ctrl, 0xf, 0xf, true))

__device__ __forceinline__ float wave_sum(float x)
{
    DPP_ADD(x, 0x111);   // row_shr:1
    DPP_ADD(x, 0x112);   // row_shr:2
    DPP_ADD(x, 0x114);   // row_shr:4
    DPP_ADD(x, 0x118);   // row_shr:8
    DPP_ADD(x, 0x142);   // row_bcast:15
    DPP_ADD(x, 0x143);   // row_bcast:31
    return __int_as_float(__builtin_amdgcn_readlane(__float_as_int(x), 63));
}

// ---------------------------------------------------------------------------
// Kernel A: one wave per (which, f) — 1536 waves. re (7x768) staged in LDS;
// each wave reads its W row ONCE, computes all 7 region dots. Block 0 zeroes
// the Kp / c accumulators for kernel B's atomic fold.
// ---------------------------------------------------------------------------
__global__ __launch_bounds__(512) void kv_kernel(
    const float* __restrict__ re,
    const float* __restrict__ Wk, const float* __restrict__ bk,
    const float* __restrict__ Wv, const float* __restrict__ bv,
    float* __restrict__ Kbuf, float* __restrict__ Vbuf,
    float* __restrict__ Kp, float* __restrict__ c_acc)
{
    __shared__ float re_s[RF];
    int tid = threadIdx.x;
    for (int i = tid; i < RF / 4; i += 512)
        ((float4*)re_s)[i] = ((const float4*)re)[i];

    if (blockIdx.x == 0) {
        float4 z = make_float4(0.f, 0.f, 0.f, 0.f);
        for (int i = tid; i < RF / 4; i += 512)
            ((float4*)Kp)[i] = z;
        if (tid < RNUM) c_acc[tid] = 0.f;
    }
    __syncthreads();

    int lane = tid & 63;
    int gwave = (int)((blockIdx.x * 512 + tid) >> 6);   // 0..1535 exactly
    int which = gwave >= FDIM;
    int f = gwave - which * FDIM;

    const float4* W4 = (const float4*)((which ? Wv : Wk) + (size_t)f * FDIM);
    float4 w0 = W4[lane];
    float4 w1 = W4[lane + 64];
    float4 w2 = W4[lane + 128];

    float s[RNUM];
#pragma unroll
    for (int r = 0; r < RNUM; ++r) {
        const float4* a4 = (const float4*)(re_s + r * FDIM);
        float4 a0 = a4[lane];
        float4 a1 = a4[lane + 64];
        float4 a2 = a4[lane + 128];
        float p = a0.x * w0.x + a0.y * w0.y + a0.z * w0.z + a0.w * w0.w
                + a1.x * w1.x + a1.y * w1.y + a1.z * w1.z + a1.w * w1.w
                + a2.x * w2.x + a2.y * w2.y + a2.z * w2.z + a2.w * w2.w;
        s[r] = wave_sum(p);
    }

    float bias = which ? bv[f] : bk[f];
    float my = s[0];
#pragma unroll
    for (int r = 1; r < RNUM; ++r) my = (lane == r) ? s[r] : my;
    if (lane < RNUM)
        (which ? Vbuf : Kbuf)[(size_t)lane * FDIM + f] = my + bias;
}

// ---------------------------------------------------------------------------
// Kernel B: Kp[r,f4] = sum_g K[r,g] * Wq[g,f4:f4+4], atomically folded over
// 8 g-chunks into Kp (zeroed by A). Tail threads fold c = bq . K.
// ---------------------------------------------------------------------------
__global__ __launch_bounds__(256) void kp_kernel(
    const float* __restrict__ Wq, const float* __restrict__ bq,
    const float* __restrict__ Kbuf,
    float* __restrict__ Kp, float* __restrict__ c_acc)
{
    const int bpc = 6;  // 6*256 = 1536 >= RF/4 + RNUM = 1351
    int chunk = blockIdx.x / bpc;
    int id = (blockIdx.x % bpc) * 256 + threadIdx.x;
    int g0 = chunk * GPC;

    if (id < RF / 4) {
        int r = id / (FDIM / 4);
        int f4i = id - r * (FDIM / 4);
        const float* kr = Kbuf + (size_t)r * FDIM + g0;
        f4v acc = {0.f, 0.f, 0.f, 0.f};
#pragma unroll 8
        for (int g = 0; g < GPC; ++g) {
            float kg = kr[g];
            f4v w = ((const f4v*)(Wq + (size_t)(g0 + g) * FDIM))[f4i];
            acc += kg * w;
        }
        float* dst = Kp + (size_t)id * 4;
        atomicAdd(dst + 0, acc.x);
        atomicAdd(dst + 1, acc.y);
        atomicAdd(dst + 2, acc.z);
        atomicAdd(dst + 3, acc.w);
    } else if (id < RF / 4 + RNUM) {
        int r = id - RF / 4;
        const float* kr = Kbuf + (size_t)r * FDIM + g0;
        const float* bqp = bq + g0;
        float sum = 0.f;
#pragma unroll 8
        for (int g = 0; g < GPC; ++g)
            sum += bqp[g] * kr[g];
        atomicAdd(c_acc + r, sum);
    }
}

// ---------------------------------------------------------------------------
// Kernel C v5: latency-bound diagnosis (round 4: VALUBusy 24%, HBM 67%,
// all pipes under-saturated, 4 waves/SIMD). 4-row iterations traverse the
// serial chain (vmcnt wait -> dots -> DPP -> softmax -> PV -> store) half
// as often per row; per-row LDS reads also halve. kp stays in LDS (round-3
// lesson: kp-in-regs spills at 4-row). Peak live regs ~115: x(48) + s(28)
// + segmented-PV a(16) + tmps. 3 quad-iters + 1 pair-tail = 14 rows/wave.
// Guard: if FETCH_SIZE >> 87MB or VGPR != 128, it spilled -> revert.
// ---------------------------------------------------------------------------
__global__ __launch_bounds__(512, 2) void attn_kernel(
    const float* __restrict__ feat,
    const float* __restrict__ Kp, const float* __restrict__ c_acc,
    const float* __restrict__ Vbuf, const float* __restrict__ rw,
    float* __restrict__ out_att, float* __restrict__ out_attn)
{
    __shared__ float kp_s[RF];
    __shared__ float v_s[RF];
    __shared__ float c_s[RNUM];
    __shared__ float w_s[RNUM];

    int tid = threadIdx.x;
    int lane = tid & 63;
    int wave = (int)((blockIdx.x * 512 + tid) >> 6);   // 0..4095

    // ---- prefetch quad 0 (rows 4*wave .. 4*wave+3) before staging ----
    float4 x0[3], x1[3], x2[3], x3[3];
    {
        const float4* f0 = (const float4*)(feat + (size_t)wave * 4 * FDIM);
#pragma unroll
        for (int j = 0; j < 3; ++j) x0[j] = f0[lane + 64 * j];
#pragma unroll
        for (int j = 0; j < 3; ++j) x1[j] = f0[192 + lane + 64 * j];
#pragma unroll
        for (int j = 0; j < 3; ++j) x2[j] = f0[384 + lane + 64 * j];
#pragma unroll
        for (int j = 0; j < 3; ++j) x3[j] = f0[576 + lane + 64 * j];
    }

    for (int i = tid; i < RF / 4; i += 512) {
        ((float4*)kp_s)[i] = ((const float4*)Kp)[i];
        ((float4*)v_s)[i] = ((const float4*)Vbuf)[i];
    }
    if (tid < RNUM) {
        c_s[tid] = c_acc[tid];
        w_s[tid] = rw[tid] * SCALE;
    }
    __syncthreads();

    // Hoist c/w to wave-uniform SGPRs.
    float cw[RNUM], ww[RNUM];
#pragma unroll
    for (int r = 0; r < RNUM; ++r) {
        cw[r] = __int_as_float(__builtin_amdgcn_readfirstlane(__float_as_int(c_s[r])));
        ww[r] = __int_as_float(__builtin_amdgcn_readfirstlane(__float_as_int(w_s[r])));
    }

    // ================= 3 quad-row iterations =================
#pragma unroll 1
    for (int it = 0; it < 3; ++it) {
        int q = wave + it * CNW;
        size_t row = (size_t)q * 4;

        // ---- raw dots: 4 rows x 7 regions (consumes x, reads kp_s) ----
        float p0[RNUM], p1[RNUM], p2[RNUM], p3[RNUM];
#pragma unroll
        for (int r = 0; r < RNUM; ++r) {
            const float4* kp4 = (const float4*)(kp_s + r * FDIM);
            float4 k0 = kp4[lane];
            float4 k1 = kp4[lane + 64];
            float4 k2 = kp4[lane + 128];
            p0[r] = x0[0].x * k0.x + x0[0].y * k0.y + x0[0].z * k0.z + x0[0].w * k0.w
                  + x0[1].x * k1.x + x0[1].y * k1.y + x0[1].z * k1.z + x0[1].w * k1.w
                  + x0[2].x * k2.x + x0[2].y * k2.y + x0[2].z * k2.z + x0[2].w * k2.w;
            p1[r] = x1[0].x * k0.x + x1[0].y * k0.y + x1[0].z * k0.z + x1[0].w * k0.w
                  + x1[1].x * k1.x + x1[1].y * k1.y + x1[1].z * k1.z + x1[1].w * k1.w
                  + x1[2].x * k2.x + x1[2].y * k2.y + x1[2].z * k2.z + x1[2].w * k2.w;
            p2[r] = x2[0].x * k0.x + x2[0].y * k0.y + x2[0].z * k0.z + x2[0].w * k0.w
                  + x2[1].x * k1.x + x2[1].y * k1.y + x2[1].z * k1.z + x2[1].w * k1.w
                  + x2[2].x * k2.x + x2[2].y * k2.y + x2[2].z * k2.z + x2[2].w * k2.w;
            p3[r] = x3[0].x * k0.x + x3[0].y * k0.y + x3[0].z * k0.z + x3[0].w * k0.w
                  + x3[1].x * k1.x + x3[1].y * k1.y + x3[1].z * k1.z + x3[1].w * k1.w
                  + x3[2].x * k2.x + x3[2].y * k2.y + x3[2].z * k2.z + x3[2].w * k2.w;
        }

        // ---- x dead: issue next loads (next quad, or the pair tail) ----
        if (it < 2) {
            const float4* fn = (const float4*)(feat + (size_t)(q + CNW) * 4 * FDIM);
#pragma unroll
            for (int j = 0; j < 3; ++j) x0[j] = fn[lane + 64 * j];
#pragma unroll
            for (int j = 0; j < 3; ++j) x1[j] = fn[192 + lane + 64 * j];
#pragma unroll
            for (int j = 0; j < 3; ++j) x2[j] = fn[384 + lane + 64 * j];
#pragma unroll
            for (int j = 0; j < 3; ++j) x3[j] = fn[576 + lane + 64 * j];
        } else {
            const float4* fn = (const float4*)(feat + ((size_t)TAILBASE + (size_t)wave * 2) * FDIM);
#pragma unroll
            for (int j = 0; j < 3; ++j) x0[j] = fn[lane + 64 * j];
#pragma unroll
            for (int j = 0; j < 3; ++j) x1[j] = fn[192 + lane + 64 * j];
        }

        // ---- DPP ladders (28 independent chains) ----
        float s0[RNUM], s1[RNUM], s2[RNUM], s3[RNUM];
#pragma unroll
        for (int r = 0; r < RNUM; ++r) {
            s0[r] = (wave_sum(p0[r]) + cw[r]) * ww[r];
            s1[r] = (wave_sum(p1[r]) + cw[r]) * ww[r];
            s2[r] = (wave_sum(p2[r]) + cw[r]) * ww[r];
            s3[r] = (wave_sum(p3[r]) + cw[r]) * ww[r];
        }

        // ---- softmax over RNUM, 4 rows ----
        float mx0 = s0[0], mx1 = s1[0], mx2 = s2[0], mx3 = s3[0];
#pragma unroll
        for (int r = 1; r < RNUM; ++r) {
            mx0 = fmaxf(mx0, s0[r]); mx1 = fmaxf(mx1, s1[r]);
            mx2 = fmaxf(mx2, s2[r]); mx3 = fmaxf(mx3, s3[r]);
        }
        float d0 = 0.f, d1 = 0.f, d2 = 0.f, d3 = 0.f;
#pragma unroll
        for (int r = 0; r < RNUM; ++r) {
            s0[r] = __expf(s0[r] - mx0); d0 += s0[r];
            s1[r] = __expf(s1[r] - mx1); d1 += s1[r];
            s2[r] = __expf(s2[r] - mx2); d2 += s2[r];
            s3[r] = __expf(s3[r] - mx3); d3 += s3[r];
        }
        float i0 = 1.0f / d0, i1 = 1.0f / d1, i2 = 1.0f / d2, i3 = 1.0f / d3;
#pragma unroll
        for (int r = 0; r < RNUM; ++r) {
            s0[r] *= i0; s1[r] *= i1; s2[r] *= i2; s3[r] *= i3;
        }

        // ---- attended: per F-segment, 4-row accumulate then store ----
        f4v* q0 = (f4v*)(out_att + row * FDIM);
        f4v* q1 = (f4v*)(out_att + (row + 1) * FDIM);
        f4v* q2 = (f4v*)(out_att + (row + 2) * FDIM);
        f4v* q3 = (f4v*)(out_att + (row + 3) * FDIM);
#pragma unroll
        for (int j = 0; j < 3; ++j) {
            float4 a0 = make_float4(0.f, 0.f, 0.f, 0.f);
            float4 a1 = make_float4(0.f, 0.f, 0.f, 0.f);
            float4 a2 = make_float4(0.f, 0.f, 0.f, 0.f);
            float4 a3 = make_float4(0.f, 0.f, 0.f, 0.f);
#pragma unroll
            for (int r = 0; r < RNUM; ++r) {
                float4 v = ((const float4*)(v_s + r * FDIM))[lane + 64 * j];
                float b0 = s0[r], b1 = s1[r], b2 = s2[r], b3 = s3[r];
                a0.x += b0 * v.x; a0.y += b0 * v.y; a0.z += b0 * v.z; a0.w += b0 * v.w;
                a1.x += b1 * v.x; a1.y += b1 * v.y; a1.z += b1 * v.z; a1.w += b1 * v.w;
                a2.x += b2 * v.x; a2.y += b2 * v.y; a2.z += b2 * v.z; a2.w += b2 * v.w;
                a3.x += b3 * v.x; a3.y += b3 * v.y; a3.z += b3 * v.z; a3.w += b3 * v.w;
            }
            __builtin_nontemporal_store(*(f4v*)&a0, q0 + lane + 64 * j);
            __builtin_nontemporal_store(*(f4v*)&a1, q1 + lane + 64 * j);
            __builtin_nontemporal_store(*(f4v*)&a2, q2 + lane + 64 * j);
            __builtin_nontemporal_store(*(f4v*)&a3, q3 + lane + 64 * j);
        }

        // ---- attn probs: 28 contiguous floats ----
        float my = s0[0];
#pragma unroll
        for (int r = 1; r < RNUM; ++r) my = (lane == r) ? s0[r] : my;
#pragma unroll
        for (int r = 0; r < RNUM; ++r) my = (lane == RNUM + r) ? s1[r] : my;
#pragma unroll
        for (int r = 0; r < RNUM; ++r) my = (lane == 2 * RNUM + r) ? s2[r] : my;
#pragma unroll
        for (int r = 0; r < RNUM; ++r) my = (lane == 3 * RNUM + r) ? s3[r] : my;
        if (lane < 4 * RNUM)
            __builtin_nontemporal_store(my, out_attn + row * RNUM + lane);
    }

    // ================= pair tail (rows TAILBASE + 2*wave, +1) =================
    {
        size_t row = (size_t)TAILBASE + (size_t)wave * 2;

        float p0[RNUM], p1[RNUM];
#pragma unroll
        for (int r = 0; r < RNUM; ++r) {
            const float4* kp4 = (const float4*)(kp_s + r * FDIM);
            float4 k0 = kp4[lane];
            float4 k1 = kp4[lane + 64];
            float4 k2 = kp4[lane + 128];
            p0[r] = x0[0].x * k0.x + x0[0].y * k0.y + x0[0].z * k0.z + x0[0].w * k0.w
                  + x0[1].x * k1.x + x0[1].y * k1.y + x0[1].z * k1.z + x0[1].w * k1.w
                  + x0[2].x * k2.x + x0[2].y * k2.y + x0[2].z * k2.z + x0[2].w * k2.w;
            p1[r] = x1[0].x * k0.x + x1[0].y * k0.y + x1[0].z * k0.z + x1[0].w * k0.w
                  + x1[1].x * k1.x + x1[1].y * k1.y + x1[1].z * k1.z + x1[1].w * k1.w
                  + x1[2].x * k2.x + x1[2].y * k2.y + x1[2].z * k2.z + x1[2].w * k2.w;
        }

        float s0[RNUM], s1[RNUM];
#pragma unroll
        for (int r = 0; r < RNUM; ++r) {
            s0[r] = (wave_sum(p0[r]) + cw[r]) * ww[r];
            s1[r] = (wave_sum(p1[r]) + cw[r]) * ww[r];
        }

        float mx0 = s0[0], mx1 = s1[0];
#pragma unroll
        for (int r = 1; r < RNUM; ++r) { mx0 = fmaxf(mx0, s0[r]); mx1 = fmaxf(mx1, s1[r]); }
        float d0 = 0.f, d1 = 0.f;
#pragma unroll
        for (int r = 0; r < RNUM; ++r) {
            s0[r] = __expf(s0[r] - mx0); d0 += s0[r];
            s1[r] = __expf(s1[r] - mx1); d1 += s1[r];
        }
        float i0 = 1.0f / d0, i1 = 1.0f / d1;
#pragma unroll
        for (int r = 0; r < RNUM; ++r) { s0[r] *= i0; s1[r] *= i1; }

        f4v* q0 = (f4v*)(out_att + row * FDIM);
        f4v* q1 = (f4v*)(out_att + (row + 1) * FDIM);
#pragma unroll
        for (int j = 0; j < 3; ++j) {
            float4 a0 = make_float4(0.f, 0.f, 0.f, 0.f);
            float4 a1 = make_float4(0.f, 0.f, 0.f, 0.f);
#pragma unroll
            for (int r = 0; r < RNUM; ++r) {
                float4 v = ((const float4*)(v_s + r * FDIM))[lane + 64 * j];
                float b0 = s0[r], b1 = s1[r];
                a0.x += b0 * v.x; a0.y += b0 * v.y; a0.z += b0 * v.z; a0.w += b0 * v.w;
                a1.x += b1 * v.x; a1.y += b1 * v.y; a1.z += b1 * v.z; a1.w += b1 * v.w;
            }
            __builtin_nontemporal_store(*(f4v*)&a0, q0 + lane + 64 * j);
            __builtin_nontemporal_store(*(f4v*)&a1, q1 + lane + 64 * j);
        }

        float my = s0[0];
#pragma unroll
        for (int r = 1; r < RNUM; ++r) my = (lane == r) ? s0[r] : my;
#pragma unroll
        for (int r = 0; r < RNUM; ++r) my = (lane == RNUM + r) ? s1[r] : my;
        if (lane < 2 * RNUM)
            __builtin_nontemporal_store(my, out_attn + row * RNUM + lane);
    }
}

// ---------------------------------------------------------------------------
extern "C" void kernel_launch(void* const* d_in, const int* in_sizes, int n_in,
                              void* d_out, int out_size, void* d_ws, size_t ws_size,
                              hipStream_t stream)
{
    const float* features = (const float*)d_in[0];
    const float* region_embeddings = (const float*)d_in[1];
    const float* Wq = (const float*)d_in[2];
    const float* bq = (const float*)d_in[3];
    const float* Wk = (const float*)d_in[4];
    const float* bk = (const float*)d_in[5];
    const float* Wv = (const float*)d_in[6];
    const float* bv = (const float*)d_in[7];
    const float* region_weights = (const float*)d_in[8];

    float* out = (float*)d_out;
    float* out_att  = out;                      // [BD, F]
    float* out_attn = out + (size_t)BD * FDIM;  // [BD, R]

    float* Kbuf  = (float*)d_ws;       // RF
    float* Vbuf  = Kbuf + RF;          // RF
    float* Kp    = Vbuf + RF;          // RF   (atomic-folded, zeroed by A)
    float* c_acc = Kp + RF;            // RNUM (atomic-folded, zeroed by A)

    // A: K and V — 1536 waves = 192 blocks x 512 thr; block 0 zeroes Kp/c.
    {
        kv_kernel<<<192, 512, 0, stream>>>(region_embeddings, Wk, bk, Wv, bv,
                                           Kbuf, Vbuf, Kp, c_acc);
    }
    // B: Kp/c atomic fold, 8 g-chunks x 6 blocks = 48 blocks.
    {
        kp_kernel<<<NCHUNK * 6, 256, 0, stream>>>(Wq, bq, Kbuf, Kp, c_acc);
    }
    // C: main pass. 512 blocks x 512 thr = 4096 waves; 3 quad + 1 pair iters.
    {
        attn_kernel<<<512, 512, 0, stream>>>(features, Kp, c_acc, Vbuf,
                                             region_weights, out_att, out_attn);
    }
}

// Round 6
// 69.354 us; speedup vs baseline: 1.3411x; 1.3411x over previous
//
#include <hip/hip_runtime.h>
#include <math.h>

// Problem constants (from reference)
#define FDIM 768
#define RNUM 7
#define BDIM 4096
#define DDIM 14
#define BD (BDIM * DDIM)          // 57344 rows
#define RF (RNUM * FDIM)          // 5376
#define NCHUNK 16                 // g-split for Kp fold (96 blocks in B)
#define GPC (FDIM / NCHUNK)       // 48
#define SCALE 0.03608439182435161f  // 768^-0.5

typedef float f4v __attribute__((ext_vector_type(4)));

// ---------------------------------------------------------------------------
// Wave-wide sum via DPP (VALU pipe) — verified correct across rounds.
// ---------------------------------------------------------------------------
#define DPP_ADD(x, ctrl)                                                      \
    x += __int_as_float(__builtin_amdgcn_update_dpp(                          \
        0, __float_as_int(x), ctrl, 0xf, 0xf, true))

__device__ __forceinline__ float wave_sum(float x)
{
    DPP_ADD(x, 0x111);   // row_shr:1
    DPP_ADD(x, 0x112);   // row_shr:2
    DPP_ADD(x, 0x114);   // row_shr:4
    DPP_ADD(x, 0x118);   // row_shr:8
    DPP_ADD(x, 0x142);   // row_bcast:15
    DPP_ADD(x, 0x143);   // row_bcast:31
    return __int_as_float(__builtin_amdgcn_readlane(__float_as_int(x), 63));
}

// ---------------------------------------------------------------------------
// Kernel A: one wave per (which, f) — 1536 waves. re (7x768) staged in LDS;
// each wave reads its W row ONCE, computes all 7 region dots. Block 0 zeroes
// the Kp / c accumulators for kernel B's atomic fold (stream order makes
// this safe: all of A completes before B starts).
// ---------------------------------------------------------------------------
__global__ __launch_bounds__(512) void kv_kernel(
    const float* __restrict__ re,
    const float* __restrict__ Wk, const float* __restrict__ bk,
    const float* __restrict__ Wv, const float* __restrict__ bv,
    float* __restrict__ Kbuf, float* __restrict__ Vbuf,
    float* __restrict__ Kp, float* __restrict__ c_acc)
{
    __shared__ float re_s[RF];
    int tid = threadIdx.x;
    for (int i = tid; i < RF / 4; i += 512)
        ((float4*)re_s)[i] = ((const float4*)re)[i];

    if (blockIdx.x == 0) {
        float4 z = make_float4(0.f, 0.f, 0.f, 0.f);
        for (int i = tid; i < RF / 4; i += 512)
            ((float4*)Kp)[i] = z;
        if (tid < RNUM) c_acc[tid] = 0.f;
    }
    __syncthreads();

    int lane = tid & 63;
    int gwave = (int)((blockIdx.x * 512 + tid) >> 6);   // 0..1535 exactly
    int which = gwave >= FDIM;
    int f = gwave - which * FDIM;

    const float4* W4 = (const float4*)((which ? Wv : Wk) + (size_t)f * FDIM);
    float4 w0 = W4[lane];
    float4 w1 = W4[lane + 64];
    float4 w2 = W4[lane + 128];

    float s[RNUM];
#pragma unroll
    for (int r = 0; r < RNUM; ++r) {
        const float4* a4 = (const float4*)(re_s + r * FDIM);
        float4 a0 = a4[lane];
        float4 a1 = a4[lane + 64];
        float4 a2 = a4[lane + 128];
        float p = a0.x * w0.x + a0.y * w0.y + a0.z * w0.z + a0.w * w0.w
                + a1.x * w1.x + a1.y * w1.y + a1.z * w1.z + a1.w * w1.w
                + a2.x * w2.x + a2.y * w2.y + a2.z * w2.z + a2.w * w2.w;
        s[r] = wave_sum(p);
    }

    float bias = which ? bv[f] : bk[f];
    float my = s[0];
#pragma unroll
    for (int r = 1; r < RNUM; ++r) my = (lane == r) ? s[r] : my;
    if (lane < RNUM)
        (which ? Vbuf : Kbuf)[(size_t)lane * FDIM + f] = my + bias;
}

// ---------------------------------------------------------------------------
// Kernel B: Kp[r,f4] = sum_g K[r,g] * Wq[g,f4:f4+4], atomically folded over
// 16 g-chunks into Kp (zeroed by A). Tail threads fold c = bq . K.
// 96 blocks — halves the per-thread loop vs NCHUNK=8.
// ---------------------------------------------------------------------------
__global__ __launch_bounds__(256) void kp_kernel(
    const float* __restrict__ Wq, const float* __restrict__ bq,
    const float* __restrict__ Kbuf,
    float* __restrict__ Kp, float* __restrict__ c_acc)
{
    const int bpc = 6;  // 6*256 = 1536 >= RF/4 + RNUM = 1351
    int chunk = blockIdx.x / bpc;
    int id = (blockIdx.x % bpc) * 256 + threadIdx.x;
    int g0 = chunk * GPC;

    if (id < RF / 4) {
        int r = id / (FDIM / 4);
        int f4i = id - r * (FDIM / 4);
        const float* kr = Kbuf + (size_t)r * FDIM + g0;
        f4v acc = {0.f, 0.f, 0.f, 0.f};
#pragma unroll 8
        for (int g = 0; g < GPC; ++g) {
            float kg = kr[g];
            f4v w = ((const f4v*)(Wq + (size_t)(g0 + g) * FDIM))[f4i];
            acc += kg * w;
        }
        float* dst = Kp + (size_t)id * 4;
        atomicAdd(dst + 0, acc.x);
        atomicAdd(dst + 1, acc.y);
        atomicAdd(dst + 2, acc.z);
        atomicAdd(dst + 3, acc.w);
    } else if (id < RF / 4 + RNUM) {
        int r = id - RF / 4;
        const float* kr = Kbuf + (size_t)r * FDIM + g0;
        const float* bqp = bq + g0;
        float sum = 0.f;
#pragma unroll 8
        for (int g = 0; g < GPC; ++g)
            sum += bqp[g] * kr[g];
        atomicAdd(c_acc + r, sum);
    }
}

// ---------------------------------------------------------------------------
// Kernel C: round-4-verified best (70.96 µs). 512 blocks x 512 thr, 2 rows
// per iteration, 7 iters, kp_s + v_s in LDS, VGPR=128, zero spill.
// Steady state ≈ 9.7 B/cyc/CU of the ~10.2 B/cyc/CU mixed-stream port
// ceiling (~95%). DO NOT: pin launch_bounds to 4 (r1: forced VGPR=64,
// spill, 6x), kp-in-regs (r3: spill), 4-row iters (r5: spill at 128 VGPR).
// ---------------------------------------------------------------------------
__global__ __launch_bounds__(512, 2) void attn_kernel(
    const float* __restrict__ feat,
    const float* __restrict__ Kp, const float* __restrict__ c_acc,
    const float* __restrict__ Vbuf, const float* __restrict__ rw,
    float* __restrict__ out_att, float* __restrict__ out_attn)
{
    __shared__ float kp_s[RF];
    __shared__ float v_s[RF];
    __shared__ float c_s[RNUM];
    __shared__ float w_s[RNUM];

    int tid = threadIdx.x;
    int lane = tid & 63;
    int wave = (int)((blockIdx.x * 512 + tid) >> 6);
    int nwaves = 512 * 8;   // 4096 waves
    int rb = wave;

    // Issue first feature loads before staging — latency hides under staging.
    float4 x0[3], x1[3];
    {
        const float4* f0 = (const float4*)(feat + (size_t)rb * 2 * FDIM);
        const float4* f1 = (const float4*)(feat + ((size_t)rb * 2 + 1) * FDIM);
#pragma unroll
        for (int j = 0; j < 3; ++j) x0[j] = f0[lane + 64 * j];
#pragma unroll
        for (int j = 0; j < 3; ++j) x1[j] = f1[lane + 64 * j];
    }

    for (int i = tid; i < RF / 4; i += 512) {
        ((float4*)kp_s)[i] = ((const float4*)Kp)[i];
        ((float4*)v_s)[i] = ((const float4*)Vbuf)[i];
    }
    if (tid < RNUM) {
        c_s[tid] = c_acc[tid];
        w_s[tid] = rw[tid] * SCALE;
    }
    __syncthreads();

    // Hoist c/w to wave-uniform SGPRs.
    float cw[RNUM], ww[RNUM];
#pragma unroll
    for (int r = 0; r < RNUM; ++r) {
        cw[r] = __int_as_float(__builtin_amdgcn_readfirstlane(__float_as_int(c_s[r])));
        ww[r] = __int_as_float(__builtin_amdgcn_readfirstlane(__float_as_int(w_s[r])));
    }

#pragma unroll 1
    for (int it = 0; it < 7; ++it) {
        size_t row = (size_t)rb * 2;
        int rb_n = rb + nwaves;

        // ---- raw dots for all 7 regions, both rows (consumes x) ----
        float p0[RNUM], p1[RNUM];
#pragma unroll
        for (int r = 0; r < RNUM; ++r) {
            const float4* kp4 = (const float4*)(kp_s + r * FDIM);
            float4 k0 = kp4[lane];
            float4 k1 = kp4[lane + 64];
            float4 k2 = kp4[lane + 128];
            p0[r] = x0[0].x * k0.x + x0[0].y * k0.y + x0[0].z * k0.z + x0[0].w * k0.w
                  + x0[1].x * k1.x + x0[1].y * k1.y + x0[1].z * k1.z + x0[1].w * k1.w
                  + x0[2].x * k2.x + x0[2].y * k2.y + x0[2].z * k2.z + x0[2].w * k2.w;
            p1[r] = x1[0].x * k0.x + x1[0].y * k0.y + x1[0].z * k0.z + x1[0].w * k0.w
                  + x1[1].x * k1.x + x1[1].y * k1.y + x1[1].z * k1.z + x1[1].w * k1.w
                  + x1[2].x * k2.x + x1[2].y * k2.y + x1[2].z * k2.z + x1[2].w * k2.w;
        }

        // ---- x dead: issue next iteration's loads ----
        if (rb_n < BD / 2) {
            const float4* f0 = (const float4*)(feat + (size_t)rb_n * 2 * FDIM);
            const float4* f1 = (const float4*)(feat + ((size_t)rb_n * 2 + 1) * FDIM);
#pragma unroll
            for (int j = 0; j < 3; ++j) x0[j] = f0[lane + 64 * j];
#pragma unroll
            for (int j = 0; j < 3; ++j) x1[j] = f1[lane + 64 * j];
        }

        // ---- DPP ladders (14 independent chains) ----
        float s0[RNUM], s1[RNUM];
#pragma unroll
        for (int r = 0; r < RNUM; ++r) {
            s0[r] = (wave_sum(p0[r]) + cw[r]) * ww[r];
            s1[r] = (wave_sum(p1[r]) + cw[r]) * ww[r];
        }

        // ---- softmax over RNUM for both rows ----
        float mx0 = s0[0], mx1 = s1[0];
#pragma unroll
        for (int r = 1; r < RNUM; ++r) { mx0 = fmaxf(mx0, s0[r]); mx1 = fmaxf(mx1, s1[r]); }
        float d0 = 0.f, d1 = 0.f;
#pragma unroll
        for (int r = 0; r < RNUM; ++r) {
            s0[r] = __expf(s0[r] - mx0); d0 += s0[r];
            s1[r] = __expf(s1[r] - mx1); d1 += s1[r];
        }
        float i0 = 1.0f / d0, i1 = 1.0f / d1;
#pragma unroll
        for (int r = 0; r < RNUM; ++r) { s0[r] *= i0; s1[r] *= i1; }

        // ---- attended: one V read serves both rows ----
        float4 o0[3], o1[3];
#pragma unroll
        for (int j = 0; j < 3; ++j) {
            o0[j] = make_float4(0.f, 0.f, 0.f, 0.f);
            o1[j] = make_float4(0.f, 0.f, 0.f, 0.f);
        }
#pragma unroll
        for (int r = 0; r < RNUM; ++r) {
            const float4* v4 = (const float4*)(v_s + r * FDIM);
            float4 va = v4[lane];
            float4 vb = v4[lane + 64];
            float4 vc = v4[lane + 128];
            float a0 = s0[r], a1 = s1[r];
            o0[0].x += a0 * va.x; o0[0].y += a0 * va.y; o0[0].z += a0 * va.z; o0[0].w += a0 * va.w;
            o0[1].x += a0 * vb.x; o0[1].y += a0 * vb.y; o0[1].z += a0 * vb.z; o0[1].w += a0 * vb.w;
            o0[2].x += a0 * vc.x; o0[2].y += a0 * vc.y; o0[2].z += a0 * vc.z; o0[2].w += a0 * vc.w;
            o1[0].x += a1 * va.x; o1[0].y += a1 * va.y; o1[0].z += a1 * va.z; o1[0].w += a1 * va.w;
            o1[1].x += a1 * vb.x; o1[1].y += a1 * vb.y; o1[1].z += a1 * vb.z; o1[1].w += a1 * vb.w;
            o1[2].x += a1 * vc.x; o1[2].y += a1 * vc.y; o1[2].z += a1 * vc.z; o1[2].w += a1 * vc.w;
        }
        f4v* q0 = (f4v*)(out_att + row * FDIM);
        f4v* q1 = (f4v*)(out_att + (row + 1) * FDIM);
#pragma unroll
        for (int j = 0; j < 3; ++j)
            __builtin_nontemporal_store(*(f4v*)&o0[j], q0 + lane + 64 * j);
#pragma unroll
        for (int j = 0; j < 3; ++j)
            __builtin_nontemporal_store(*(f4v*)&o1[j], q1 + lane + 64 * j);

        float my = s0[0];
#pragma unroll
        for (int r = 1; r < RNUM; ++r) my = (lane == r) ? s0[r] : my;
#pragma unroll
        for (int r = 0; r < RNUM; ++r) my = (lane == RNUM + r) ? s1[r] : my;
        if (lane < 2 * RNUM)
            __builtin_nontemporal_store(my, out_attn + row * RNUM + lane);

        rb = rb_n;
    }
}

// ---------------------------------------------------------------------------
extern "C" void kernel_launch(void* const* d_in, const int* in_sizes, int n_in,
                              void* d_out, int out_size, void* d_ws, size_t ws_size,
                              hipStream_t stream)
{
    const float* features = (const float*)d_in[0];
    const float* region_embeddings = (const float*)d_in[1];
    const float* Wq = (const float*)d_in[2];
    const float* bq = (const float*)d_in[3];
    const float* Wk = (const float*)d_in[4];
    const float* bk = (const float*)d_in[5];
    const float* Wv = (const float*)d_in[6];
    const float* bv = (const float*)d_in[7];
    const float* region_weights = (const float*)d_in[8];

    float* out = (float*)d_out;
    float* out_att  = out;                      // [BD, F]
    float* out_attn = out + (size_t)BD * FDIM;  // [BD, R]

    float* Kbuf  = (float*)d_ws;       // RF
    float* Vbuf  = Kbuf + RF;          // RF
    float* Kp    = Vbuf + RF;          // RF   (atomic-folded, zeroed by A)
    float* c_acc = Kp + RF;            // RNUM (atomic-folded, zeroed by A)

    // A: K and V — 1536 waves = 192 blocks x 512 thr; block 0 zeroes Kp/c.
    {
        kv_kernel<<<192, 512, 0, stream>>>(region_embeddings, Wk, bk, Wv, bv,
                                           Kbuf, Vbuf, Kp, c_acc);
    }
    // B: Kp/c atomic fold, 16 g-chunks x 6 blocks = 96 blocks.
    {
        kp_kernel<<<NCHUNK * 6, 256, 0, stream>>>(Wq, bq, Kbuf, Kp, c_acc);
    }
    // C: main pass. 512 blocks x 512 thr = 4096 waves; 7 pair-row iters each.
    {
        attn_kernel<<<512, 512, 0, stream>>>(features, Kp, c_acc, Vbuf,
                                             region_weights, out_att, out_attn);
    }
}